// Round 5
// baseline (1095.681 us; speedup 1.0000x reference)
//
#include <hip/hip_runtime.h>

typedef __bf16 bf16_t;
typedef bf16_t bf16x4 __attribute__((ext_vector_type(4)));
typedef bf16_t bf16x8 __attribute__((ext_vector_type(8)));
typedef float floatx4 __attribute__((ext_vector_type(4)));

#define F_INq 64
#define F_OUTq 128
#define PERIODSq 12
#define XROW (F_INq * PERIODSq) /* 768 */

// ---------------- degree / CSR build ----------------
__global__ __launch_bounds__(256) void k_init(float* deg, int* counts, int N) {
  int i = blockIdx.x * 256 + threadIdx.x;
  if (i < N) { deg[i] = 1.0f; counts[i] = 0; }  // self-loop weight 1
}

__global__ __launch_bounds__(256) void k_accum(const int* __restrict__ ei, const float* __restrict__ ew,
                                               float* deg, int* counts, int E) {
  int e = blockIdx.x * 256 + threadIdx.x;
  if (e < E) {
    int c = ei[E + e];  // target
    atomicAdd(&deg[c], ew[e]);
    atomicAdd(&counts[c], 1);
  }
}

// fallback-path dinv (main path folds dinv into k_scanA)
__global__ __launch_bounds__(256) void k_dinv(float* deg, int N) {
  int i = blockIdx.x * 256 + threadIdx.x;
  if (i < N) { float d = deg[i]; deg[i] = d > 0.0f ? rsqrtf(d) : 0.0f; }
}

// ---------------- multi-block scan ----------------
// A: per-1024-chunk sums + dinv (elementwise, same index range)
__global__ __launch_bounds__(256) void k_scanA(const int* __restrict__ counts, float* __restrict__ deg,
                                               int* __restrict__ bsum, int N) {
  __shared__ int ws[4];
  int b = blockIdx.x, t = threadIdx.x;
  int base = b * 1024 + t * 4;
  int s = 0;
  if (base + 3 < N) {
    int4 c = *(const int4*)(counts + base);
    s = c.x + c.y + c.z + c.w;
  } else {
    for (int k = 0; k < 4; ++k) if (base + k < N) s += counts[base + k];
  }
#pragma unroll
  for (int k = 0; k < 4; ++k) {
    int idx = base + k;
    if (idx < N) { float d = deg[idx]; deg[idx] = d > 0.0f ? rsqrtf(d) : 0.0f; }
  }
  for (int off = 1; off < 64; off <<= 1) s += __shfl_xor(s, off);
  int lane = t & 63, w = t >> 6;
  if (lane == 0) ws[w] = s;
  __syncthreads();
  if (t == 0) bsum[b] = ws[0] + ws[1] + ws[2] + ws[3];
}

// C: per-chunk local scan + base (block base recomputed redundantly from bsum; nb<=64)
__global__ __launch_bounds__(256) void k_scanC(const int* __restrict__ counts, const int* __restrict__ bsum,
                                               int* __restrict__ offs, int* __restrict__ cursor, int N, int nb) {
  __shared__ int ws[4];
  int b = blockIdx.x, t = threadIdx.x;
  int base = b * 1024 + t * 4;
  int c0_ = 0, c1_ = 0, c2_ = 0, c3_ = 0;
  if (base + 3 < N) {
    int4 c = *(const int4*)(counts + base);
    c0_ = c.x; c1_ = c.y; c2_ = c.z; c3_ = c.w;
  } else {
    if (base < N) c0_ = counts[base];
    if (base + 1 < N) c1_ = counts[base + 1];
    if (base + 2 < N) c2_ = counts[base + 2];
    if (base + 3 < N) c3_ = counts[base + 3];
  }
  int tot = c0_ + c1_ + c2_ + c3_;
  int lane = t & 63, w = t >> 6;
  int inc = tot;
  for (int off = 1; off < 64; off <<= 1) {
    int u = __shfl_up(inc, off);
    if (lane >= off) inc += u;
  }
  if (lane == 63) ws[w] = inc;
  __syncthreads();
  int wb = 0;  // exclusive prefix of block sums (uniform scalar loop, nb<=64, L2-hot)
  for (int i = 0; i < b; ++i) wb += bsum[i];
  for (int i = 0; i < w; ++i) wb += ws[i];
  int e = wb + inc - tot;
  if (base < N)     { offs[base] = e;                 cursor[base] = e; }
  if (base + 1 < N) { int o = e + c0_;                offs[base + 1] = o; cursor[base + 1] = o; }
  if (base + 2 < N) { int o = e + c0_ + c1_;          offs[base + 2] = o; cursor[base + 2] = o; }
  if (base + 3 < N) { int o = e + c0_ + c1_ + c2_;    offs[base + 3] = o; cursor[base + 3] = o; }
  if (b == nb - 1 && t == 0) {
    int tt2 = 0;
    for (int i = 0; i < nb - 1; ++i) tt2 += bsum[i];
    offs[N] = tt2 + ws[0] + ws[1] + ws[2] + ws[3];
  }
}

// fallback single-block scan (only if nb > 64; N=40000 -> never)
__global__ __launch_bounds__(1024) void k_scan(const int* __restrict__ counts, int* __restrict__ offs,
                                               int* __restrict__ cursor, int N) {
  __shared__ int sd[1024];
  int t = threadIdx.x;
  int CH = (N + 1023) >> 10;
  int base = t * CH;
  int sum = 0;
  for (int i = 0; i < CH; ++i) { int idx = base + i; if (idx < N) sum += counts[idx]; }
  sd[t] = sum;
  __syncthreads();
  for (int off = 1; off < 1024; off <<= 1) {
    int v = (t >= off) ? sd[t - off] : 0;
    __syncthreads();
    sd[t] += v;
    __syncthreads();
  }
  int run = sd[t] - sum;  // exclusive prefix
  for (int i = 0; i < CH; ++i) {
    int idx = base + i;
    if (idx < N) { offs[idx] = run; cursor[idx] = run; run += counts[idx]; }
  }
  if (t == 1023) offs[N] = sd[1023];
}

// standalone fallbacks (used only on the fp32 fallback path)
__global__ __launch_bounds__(256) void k_scatter(const int* __restrict__ ei, const float* __restrict__ ew,
                                                 const float* __restrict__ dinv, int* cursor,
                                                 int* __restrict__ csr_src, float* __restrict__ csr_nrm, int E) {
  int e = blockIdx.x * 256 + threadIdx.x;
  if (e < E) {
    int r = ei[e], c = ei[E + e];
    int p = atomicAdd(&cursor[c], 1);
    csr_src[p] = r;
    csr_nrm[p] = dinv[r] * ew[e] * dinv[c];
  }
}

__global__ __launch_bounds__(256) void k_prew(
    const float* __restrict__ Wxi, const float* __restrict__ Whi,
    const float* __restrict__ Wxf, const float* __restrict__ Whf,
    const float* __restrict__ Wxc, const float* __restrict__ Whc,
    const float* __restrict__ Wxo, const float* __restrict__ Who,
    const float* __restrict__ bxi, const float* __restrict__ bhi,
    const float* __restrict__ bxf, const float* __restrict__ bhf,
    const float* __restrict__ bxc, const float* __restrict__ bhc,
    const float* __restrict__ bxo, const float* __restrict__ bho,
    const float* __restrict__ att,
    bf16_t* __restrict__ WbT, float* __restrict__ bcomb, float* __restrict__ probs) {
  const int WT = 512 * 192;
  int gid = blockIdx.x * 256 + threadIdx.x;
  if (gid < WT) {
    int col = gid / 192, k = gid % 192;
    int g = col >> 7, j = col & 127;
    const float* Wx = g == 0 ? Wxi : g == 1 ? Wxf : g == 2 ? Wxc : Wxo;
    const float* Wh = g == 0 ? Whi : g == 1 ? Whf : g == 2 ? Whc : Who;
    float s;
    if (k < 64) {
      s = 0.0f;
      for (int kk = 0; kk < 128; ++kk) s += Wx[k * 128 + kk] * Wh[kk * 128 + j];
    } else {
      s = Wh[(k + 64) * 128 + j];
    }
    WbT[(size_t)col * 192 + k] = (bf16_t)s;
  } else if (gid < WT + 512) {
    int cc = gid - WT;
    int g = cc >> 7, j = cc & 127;
    const float* bx = g == 0 ? bxi : g == 1 ? bxf : g == 2 ? bxc : bxo;
    const float* bh = g == 0 ? bhi : g == 1 ? bhf : g == 2 ? bhc : bho;
    const float* Wh = g == 0 ? Whi : g == 1 ? Whf : g == 2 ? Whc : Who;
    float s = bh[j];
    for (int kk = 0; kk < 128; ++kk) s += bx[kk] * Wh[kk * 128 + j];
    bcomb[cc] = s;
  } else if (gid == WT + 512) {
    float m = att[0];
    for (int i = 1; i < PERIODSq; ++i) m = fmaxf(m, att[i]);
    float e[PERIODSq], s = 0.0f;
    for (int i = 0; i < PERIODSq; ++i) { e[i] = __expf(att[i] - m); s += e[i]; }
    for (int i = 0; i < PERIODSq; ++i) probs[i] = e[i] / s;
  }
}

// ---------------- fused mid-pipeline: scatter | prew | xpose in ONE dispatch ----------------
__global__ __launch_bounds__(256) void k_mid(
    const int* __restrict__ ei, const float* __restrict__ ew, const float* __restrict__ dinv,
    int* cursor, int* __restrict__ csr_src, float* __restrict__ csr_nrm, int E,
    const float* __restrict__ Wxi, const float* __restrict__ Whi,
    const float* __restrict__ Wxf, const float* __restrict__ Whf,
    const float* __restrict__ Wxc, const float* __restrict__ Whc,
    const float* __restrict__ Wxo, const float* __restrict__ Who,
    const float* __restrict__ bxi, const float* __restrict__ bhi,
    const float* __restrict__ bxf, const float* __restrict__ bhf,
    const float* __restrict__ bxc, const float* __restrict__ bhc,
    const float* __restrict__ bxo, const float* __restrict__ bho,
    const float* __restrict__ att,
    bf16_t* __restrict__ WbT, float* __restrict__ bcomb, float* __restrict__ probs,
    const float* __restrict__ X, bf16_t* __restrict__ Xb,
    int nbScatter, int nbPrew) {
  __shared__ float lds[XROW];
  const int b = blockIdx.x, tid = threadIdx.x;
  if (b < nbScatter) {
    int e = b * 256 + tid;
    if (e < E) {
      int r = ei[e], c = ei[E + e];
      int p = atomicAdd(&cursor[c], 1);
      csr_src[p] = r;
      csr_nrm[p] = dinv[r] * ew[e] * dinv[c];
    }
    return;
  }
  if (b < nbScatter + nbPrew) {
    const int WT = 512 * 192;
    int gid = (b - nbScatter) * 256 + tid;
    if (gid < WT) {
      int col = gid / 192, k = gid % 192;
      int g = col >> 7, j = col & 127;
      const float* Wx = g == 0 ? Wxi : g == 1 ? Wxf : g == 2 ? Wxc : Wxo;
      const float* Wh = g == 0 ? Whi : g == 1 ? Whf : g == 2 ? Whc : Who;
      float s;
      if (k < 64) {
        s = 0.0f;
        for (int kk = 0; kk < 128; ++kk) s += Wx[k * 128 + kk] * Wh[kk * 128 + j];
      } else {
        s = Wh[(k + 64) * 128 + j];
      }
      WbT[(size_t)col * 192 + k] = (bf16_t)s;
    } else if (gid < WT + 512) {
      int cc = gid - WT;
      int g = cc >> 7, j = cc & 127;
      const float* bx = g == 0 ? bxi : g == 1 ? bxf : g == 2 ? bxc : bxo;
      const float* bh = g == 0 ? bhi : g == 1 ? bhf : g == 2 ? bhc : bho;
      const float* Wh = g == 0 ? Whi : g == 1 ? Whf : g == 2 ? Whc : Who;
      float s = bh[j];
      for (int kk = 0; kk < 128; ++kk) s += bx[kk] * Wh[kk * 128 + j];
      bcomb[cc] = s;
    } else if (gid == WT + 512) {
      float m = att[0];
      for (int i = 1; i < PERIODSq; ++i) m = fmaxf(m, att[i]);
      float e[PERIODSq], s = 0.0f;
      for (int i = 0; i < PERIODSq; ++i) { e[i] = __expf(att[i] - m); s += e[i]; }
      for (int i = 0; i < PERIODSq; ++i) probs[i] = e[i] / s;
    }
    return;
  }
  // xpose: X[n][f][t] fp32 -> Xb[n][t*64+f] bf16 (threads 0..191 active, barrier uniform)
  const int n = b - nbScatter - nbPrew;
  if (tid < 192) {
    const float4* Xr = (const float4*)(X + (size_t)n * XROW);
    float4 v = Xr[tid];
    lds[tid * 4 + 0] = v.x;
    lds[tid * 4 + 1] = v.y;
    lds[tid * 4 + 2] = v.z;
    lds[tid * 4 + 3] = v.w;
  }
  __syncthreads();
  if (tid < 192) {
    const int o = tid * 4;
    bf16x4 r;
#pragma unroll
    for (int k = 0; k < 4; ++k) {
      int oo = o + k;
      int tt = oo >> 6, f = oo & 63;
      r[k] = (bf16_t)lds[f * PERIODSq + tt];
    }
    *(bf16x4*)(Xb + (size_t)n * XROW + o) = r;
  }
}

// ---------------- fallback aggregation (fp32 gather, used only if ws too small) ----------------
__global__ __launch_bounds__(256) void k_agg(const float* __restrict__ X, const int* __restrict__ csr_src,
                                             const float* __restrict__ csr_nrm, const int* __restrict__ offs,
                                             const float* __restrict__ dinv, bf16_t* __restrict__ Xagg, int N) {
  int c = blockIdx.x;
  int tid = threadIdx.x;
  int s0 = offs[c], s1 = offs[c + 1];
  const int i0 = tid, i1 = tid + 256, i2 = tid + 512;
  float a0 = 0.f, a1 = 0.f, a2 = 0.f;
  for (int e = s0; e < s1; ++e) {
    int s = csr_src[e];
    float nr = csr_nrm[e];
    const float* xp = X + (size_t)s * XROW;
    a0 += nr * xp[i0]; a1 += nr * xp[i1]; a2 += nr * xp[i2];
  }
  float dc = dinv[c];
  float self = dc * dc;
  const float* xc = X + (size_t)c * XROW;
  a0 += self * xc[i0]; a1 += self * xc[i1]; a2 += self * xc[i2];
  __shared__ float lds[XROW];
  lds[i0] = a0; lds[i1] = a1; lds[i2] = a2;
  __syncthreads();
  for (int o = tid; o < XROW; o += 256) {
    int tt = o >> 6, f = o & 63;
    Xagg[(size_t)tt * N * 64 + (size_t)c * 64 + f] = (bf16_t)lds[f * PERIODSq + tt];
  }
}

// ---------------- fallback gate (reads precomputed Xagg; proven in rounds 2-4) ----------------
__global__ __launch_bounds__(512, 2) void k_gate_all(const bf16_t* __restrict__ Xagg,
                                                     const bf16_t* __restrict__ WbT,
                                                     const float* __restrict__ bcomb,
                                                     const float* __restrict__ probs,
                                                     float* __restrict__ out, int N) {
  __shared__ __align__(16) char Hs[2][32 * 256];
  const int tid = threadIdx.x;
  const int lane = tid & 63, w = tid >> 6;
  const int q = lane >> 4, c0 = lane & 15;
  const int n0 = blockIdx.x * 32;
  const int swz = c0 & 7;

  bf16x8 Wf[4][6];
#pragma unroll
  for (int g = 0; g < 4; ++g) {
    const bf16_t* wp = WbT + (size_t)((g * 8 + w) * 16 + c0) * 192;
#pragma unroll
    for (int ks = 0; ks < 6; ++ks) Wf[g][ks] = *(const bf16x8*)(wp + ks * 32 + q * 8);
  }
  floatx4 bv[4];
#pragma unroll
  for (int g = 0; g < 4; ++g) bv[g] = *(const floatx4*)(bcomb + g * 128 + w * 16 + q * 4);
  float pr[PERIODSq];
#pragma unroll
  for (int i = 0; i < PERIODSq; ++i) pr[i] = probs[i];

  floatx4 Cst[2], Ha[2];
#pragma unroll
  for (int rt = 0; rt < 2; ++rt) {
    Cst[rt] = (floatx4){0.f, 0.f, 0.f, 0.f};
    Ha[rt] = (floatx4){0.f, 0.f, 0.f, 0.f};
  }

  const bf16_t* Xrow0 = Xagg + (size_t)(n0 + c0) * 64 + q * 8;
  const bf16_t* Xrow1 = Xagg + (size_t)(n0 + 16 + c0) * 64 + q * 8;

  bf16x8 Xf0 = *(const bf16x8*)(Xrow0);
  bf16x8 Xf1 = *(const bf16x8*)(Xrow0 + 32);
  bf16x8 Xf2 = *(const bf16x8*)(Xrow1);
  bf16x8 Xf3 = *(const bf16x8*)(Xrow1 + 32);

  floatx4 accA[2][4], accB[2][4];
#pragma unroll
  for (int g = 0; g < 4; ++g) {
    accA[0][g] = __builtin_amdgcn_mfma_f32_16x16x32_bf16(Wf[g][0], Xf0, bv[g], 0, 0, 0);
    accA[0][g] = __builtin_amdgcn_mfma_f32_16x16x32_bf16(Wf[g][1], Xf1, accA[0][g], 0, 0, 0);
    accA[1][g] = __builtin_amdgcn_mfma_f32_16x16x32_bf16(Wf[g][0], Xf2, bv[g], 0, 0, 0);
    accA[1][g] = __builtin_amdgcn_mfma_f32_16x16x32_bf16(Wf[g][1], Xf3, accA[1][g], 0, 0, 0);
  }

  const float NL2E = -1.44269504f;
  const float T2L2E = 2.88539008f;

#define PERIOD(T, AC, AN, RB, WB, DO_H, DO_NEXT)                                                      \
  do {                                                                                                \
    if (DO_NEXT) {                                                                                    \
      const size_t toff_ = (size_t)((T) + 1) * N * 64;                                                \
      Xf0 = *(const bf16x8*)(Xrow0 + toff_);                                                          \
      Xf1 = *(const bf16x8*)(Xrow0 + toff_ + 32);                                                     \
      Xf2 = *(const bf16x8*)(Xrow1 + toff_);                                                          \
      Xf3 = *(const bf16x8*)(Xrow1 + toff_ + 32);                                                     \
    }                                                                                                 \
    if (DO_H) {                                                                                       \
      _Pragma("unroll") for (int ks = 0; ks < 4; ++ks) {                                              \
        bf16x8 B0 = *(const bf16x8*)(&Hs[RB][(c0) * 256 + (((4 * ks + q) ^ swz) << 4)]);              \
        bf16x8 B1 = *(const bf16x8*)(&Hs[RB][(16 + c0) * 256 + (((4 * ks + q) ^ swz) << 4)]);         \
        _Pragma("unroll") for (int g = 0; g < 4; ++g) {                                               \
          AC[0][g] = __builtin_amdgcn_mfma_f32_16x16x32_bf16(Wf[g][ks + 2], B0, AC[0][g], 0, 0, 0);   \
          AC[1][g] = __builtin_amdgcn_mfma_f32_16x16x32_bf16(Wf[g][ks + 2], B1, AC[1][g], 0, 0, 0);   \
        }                                                                                             \
      }                                                                                               \
    }                                                                                                 \
    const float pt_ = pr[T];                                                                          \
    _Pragma("unroll") for (int rt = 0; rt < 2; ++rt) {                                                \
      bf16x4 hv_;                                                                                     \
      _Pragma("unroll") for (int r = 0; r < 4; ++r) {                                                 \
        float pI = AC[rt][0][r], pF = AC[rt][1][r], pC = AC[rt][2][r], pO = AC[rt][3][r];             \
        float I_ = __builtin_amdgcn_rcpf(1.0f + __builtin_amdgcn_exp2f(pI * NL2E));                   \
        float F_ = __builtin_amdgcn_rcpf(1.0f + __builtin_amdgcn_exp2f(pF * NL2E));                   \
        float Ct_ = fmaf(-2.0f, __builtin_amdgcn_rcpf(1.0f + __builtin_amdgcn_exp2f(pC * T2L2E)), 1.0f); \
        float O_ = __builtin_amdgcn_rcpf(1.0f + __builtin_amdgcn_exp2f(pO * NL2E));                   \
        float Cn_ = fmaf(F_, Cst[rt][r], I_ * Ct_);                                                   \
        Cst[rt][r] = Cn_;                                                                             \
        float tC_ = fmaf(-2.0f, __builtin_amdgcn_rcpf(1.0f + __builtin_amdgcn_exp2f(Cn_ * T2L2E)), 1.0f); \
        float Hn_ = O_ * tC_;                                                                         \
        Ha[rt][r] = fmaf(pt_, Hn_, Ha[rt][r]);                                                        \
        hv_[r] = (bf16_t)Hn_;                                                                         \
      }                                                                                               \
      *(bf16x4*)(&Hs[WB][(rt * 16 + c0) * 256 + (((2 * w + (q >> 1)) ^ swz) << 4) + ((q & 1) * 8)]) = hv_; \
    }                                                                                                 \
    if (DO_NEXT) {                                                                                    \
      _Pragma("unroll") for (int g = 0; g < 4; ++g) {                                                 \
        AN[0][g] = __builtin_amdgcn_mfma_f32_16x16x32_bf16(Wf[g][0], Xf0, bv[g], 0, 0, 0);            \
        AN[0][g] = __builtin_amdgcn_mfma_f32_16x16x32_bf16(Wf[g][1], Xf1, AN[0][g], 0, 0, 0);         \
        AN[1][g] = __builtin_amdgcn_mfma_f32_16x16x32_bf16(Wf[g][0], Xf2, bv[g], 0, 0, 0);            \
        AN[1][g] = __builtin_amdgcn_mfma_f32_16x16x32_bf16(Wf[g][1], Xf3, AN[1][g], 0, 0, 0);         \
      }                                                                                               \
    }                                                                                                 \
    __syncthreads();                                                                                  \
  } while (0)

  PERIOD(0, accA, accB, 1, 0, 0, 1);
  for (int tt = 1; tt <= 9; tt += 2) {
    PERIOD(tt, accB, accA, 0, 1, 1, 1);
    PERIOD(tt + 1, accA, accB, 1, 0, 1, 1);
  }
  PERIOD(11, accB, accA, 0, 1, 1, 0);
#undef PERIOD

#pragma unroll
  for (int rt = 0; rt < 2; ++rt) {
    int row = n0 + rt * 16 + c0;
    *(floatx4*)(out + (size_t)row * 128 + w * 16 + q * 4) = Ha[rt];
  }
}

// ---------------- FUSED gather + LSTM (this round's change) ----------------
// Replaces k_agg2 + k_gate_all on the main path. Per 32-node block, the aggregation is
// staged by t-groups of 4 periods into a double-buffered, XOR-swizzled LDS X tile.
// Gather loads (512B/edge wave requests, contiguous CSR range offs[4w]..offs[4w+4] per
// wave, wave-uniform edge index -> scalar src/nrm + uniform 4-way accumulator branch)
// are ISSUED before and DRAINED after each period's MFMA/epilogue phases, so the
// random-gather latency hides under gate compute instead of occupying its own 146us
// kernel. Xagg round-trip (61MB write+read) and one dispatch eliminated.
// Xl granule algebra: row pitch 512B = 32 16B-granules; write (t'=lane>>4, q_w=(lane&15)>>1)
// -> granule t'*8+q_w ^ ((row&7)<<2); read frag fr at (tl,q) -> granule tl*8+fr*4+q ^ same
// key (row&7 == c0&7 for rows c0 and 16+c0) -> bijective per row, 2 lanes/granule = free.
__global__ __launch_bounds__(512, 2) void k_gate_fused(
    const bf16_t* __restrict__ Xb, const int* __restrict__ csr_src, const float* __restrict__ csr_nrm,
    const int* __restrict__ offs, const float* __restrict__ dinv,
    const bf16_t* __restrict__ WbT, const float* __restrict__ bcomb, const float* __restrict__ probs,
    float* __restrict__ out, int N) {
  __shared__ __align__(16) char Hs[2][32 * 256];
  __shared__ __align__(16) char Xl[2][32 * 512];
  __shared__ float probsS[16];
  const int tid = threadIdx.x;
  const int lane = tid & 63, w = tid >> 6;
  const int q = lane >> 4, c0 = lane & 15;
  const int n0 = blockIdx.x * 32;
  const int swz = c0 & 7;
  const int xkey = swz << 2;  // X-LDS granule swizzle key (5-bit granules)

  if (tid < PERIODSq) probsS[tid] = probs[tid];

  // stationary W fragments: col = (g*8+w)*16 + c0, k-chunk ks*32 + q*8
  bf16x8 Wf[4][6];
#pragma unroll
  for (int g = 0; g < 4; ++g) {
    const bf16_t* wp = WbT + (size_t)((g * 8 + w) * 16 + c0) * 192;
#pragma unroll
    for (int ks = 0; ks < 6; ++ks) Wf[g][ks] = *(const bf16x8*)(wp + ks * 32 + q * 8);
  }
  floatx4 bv[4];
#pragma unroll
  for (int g = 0; g < 4; ++g) bv[g] = *(const floatx4*)(bcomb + g * 128 + w * 16 + q * 4);

  // gather state: wave handles nodes gbase..gbase+3, one contiguous CSR range
  const int gbase = n0 + 4 * w;
  const int eStart = offs[gbase];
  const int b1 = offs[gbase + 1], b2 = offs[gbase + 2], b3 = offs[gbase + 3];
  const int eTot = offs[gbase + 4];
  float sf[4];
#pragma unroll
  for (int i = 0; i < 4; ++i) { float dv = dinv[gbase + i]; sf[i] = dv * dv; }

  floatx4 accN[4];
  bf16x4 xv[8];
  float nr[8];
  int nu[8];
  bf16x4 sxv[4];
  int e = eStart;
#pragma unroll
  for (int i = 0; i < 4; ++i) accN[i] = (floatx4){0.f, 0.f, 0.f, 0.f};

#define G_ISSUE(SOFF)                                                                  \
  _Pragma("unroll") for (int u = 0; u < 8; ++u) {                                      \
    int idx_ = e + u;                                                                  \
    if (idx_ < eTot) {                                                                 \
      int s_ = csr_src[idx_];                                                          \
      nr[u] = csr_nrm[idx_];                                                           \
      nu[u] = (idx_ >= b1) + (idx_ >= b2) + (idx_ >= b3);                              \
      xv[u] = *(const bf16x4*)(Xb + (size_t)s_ * XROW + (SOFF) + lane * 4);            \
    } else {                                                                           \
      nr[u] = 0.0f; nu[u] = 0;                                                         \
      xv[u] = (bf16x4){(bf16_t)0.0f, (bf16_t)0.0f, (bf16_t)0.0f, (bf16_t)0.0f};       \
    }                                                                                  \
  }

#define G_DRAIN()                                                                      \
  _Pragma("unroll") for (int u = 0; u < 8; ++u) {                                      \
    float nv_ = nr[u]; bf16x4 xx_ = xv[u]; int t_ = nu[u];                             \
    if (t_ == 0) { _Pragma("unroll") for (int k = 0; k < 4; ++k) accN[0][k] += nv_ * (float)xx_[k]; } \
    else if (t_ == 1) { _Pragma("unroll") for (int k = 0; k < 4; ++k) accN[1][k] += nv_ * (float)xx_[k]; } \
    else if (t_ == 2) { _Pragma("unroll") for (int k = 0; k < 4; ++k) accN[2][k] += nv_ * (float)xx_[k]; } \
    else { _Pragma("unroll") for (int k = 0; k < 4; ++k) accN[3][k] += nv_ * (float)xx_[k]; } \
  }                                                                                    \
  e += 8;

#define G_SELF(SOFF)                                                                   \
  _Pragma("unroll") for (int i = 0; i < 4; ++i)                                        \
    sxv[i] = *(const bf16x4*)(Xb + (size_t)(gbase + i) * XROW + (SOFF) + lane * 4);

#define G_WRITE(BUF)                                                                   \
  _Pragma("unroll") for (int i = 0; i < 4; ++i) {                                      \
    int row_ = 4 * w + i;                                                              \
    bf16x4 hx_;                                                                        \
    _Pragma("unroll") for (int k = 0; k < 4; ++k)                                      \
      hx_[k] = (bf16_t)(accN[i][k] + sf[i] * (float)sxv[i][k]);                        \
    *(bf16x4*)(&Xl[BUF][row_ * 512 + ((((lane >> 1) ^ ((row_ & 7) << 2)) << 4) + (lane & 1) * 8)]) = hx_; \
    accN[i] = (floatx4){0.f, 0.f, 0.f, 0.f};                                           \
  }                                                                                    \
  e = eStart;

  // prologue: gather t-group 0 (exposed; deep-pipelined chunks of 8)
  while (e < eTot) { G_ISSUE(0); G_DRAIN(); }
  G_SELF(0);
  G_WRITE(0);

  floatx4 Cst[2], Ha[2];
#pragma unroll
  for (int rt = 0; rt < 2; ++rt) {
    Cst[rt] = (floatx4){0.f, 0.f, 0.f, 0.f};
    Ha[rt] = (floatx4){0.f, 0.f, 0.f, 0.f};
  }
  __syncthreads();

  const float NL2E = -1.44269504f;  // -log2(e)
  const float T2L2E = 2.88539008f;  // 2*log2(e)

  // GAT: gather t-group (T>>2)+1 interleaved through this period. LAST: finish the
  // group (drain remainder + self) and commit to Xl buffer before the barrier.
#define GPER(T, GAT, LAST)                                                                            \
  do {                                                                                                \
    const int XBuf = ((T) >> 2) & 1;                                                                  \
    const int tl = (T) & 3;                                                                           \
    const int soff_ = (((T) >> 2) + 1) * 256;                                                         \
    if (GAT) { G_ISSUE(soff_); }                                                                      \
    floatx4 acc[2][4];                                                                                \
    {                                                                                                 \
      bf16x8 X00 = *(const bf16x8*)(&Xl[XBuf][c0 * 512 + (((tl * 8 + q) ^ xkey) << 4)]);              \
      bf16x8 X01 = *(const bf16x8*)(&Xl[XBuf][c0 * 512 + (((tl * 8 + 4 + q) ^ xkey) << 4)]);          \
      bf16x8 X10 = *(const bf16x8*)(&Xl[XBuf][(16 + c0) * 512 + (((tl * 8 + q) ^ xkey) << 4)]);       \
      bf16x8 X11 = *(const bf16x8*)(&Xl[XBuf][(16 + c0) * 512 + (((tl * 8 + 4 + q) ^ xkey) << 4)]);   \
      _Pragma("unroll") for (int g = 0; g < 4; ++g) {                                                 \
        acc[0][g] = __builtin_amdgcn_mfma_f32_16x16x32_bf16(Wf[g][0], X00, bv[g], 0, 0, 0);           \
        acc[0][g] = __builtin_amdgcn_mfma_f32_16x16x32_bf16(Wf[g][1], X01, acc[0][g], 0, 0, 0);       \
        acc[1][g] = __builtin_amdgcn_mfma_f32_16x16x32_bf16(Wf[g][0], X10, bv[g], 0, 0, 0);           \
        acc[1][g] = __builtin_amdgcn_mfma_f32_16x16x32_bf16(Wf[g][1], X11, acc[1][g], 0, 0, 0);       \
      }                                                                                               \
    }                                                                                                 \
    if (GAT) { G_DRAIN(); G_ISSUE(soff_); }                                                           \
    if ((T) > 0) {                                                                                    \
      const int RB = ((T) & 1) ^ 1;                                                                   \
      _Pragma("unroll") for (int ks = 0; ks < 4; ++ks) {                                              \
        bf16x8 B0 = *(const bf16x8*)(&Hs[RB][c0 * 256 + (((4 * ks + q) ^ swz) << 4)]);                \
        bf16x8 B1 = *(const bf16x8*)(&Hs[RB][(16 + c0) * 256 + (((4 * ks + q) ^ swz) << 4)]);         \
        _Pragma("unroll") for (int g = 0; g < 4; ++g) {                                               \
          acc[0][g] = __builtin_amdgcn_mfma_f32_16x16x32_bf16(Wf[g][ks + 2], B0, acc[0][g], 0, 0, 0); \
          acc[1][g] = __builtin_amdgcn_mfma_f32_16x16x32_bf16(Wf[g][ks + 2], B1, acc[1][g], 0, 0, 0); \
        }                                                                                             \
      }                                                                                               \
    }                                                                                                 \
    {                                                                                                 \
      const int WB = (T) & 1;                                                                         \
      const float pt_ = probsS[T];                                                                    \
      _Pragma("unroll") for (int rt = 0; rt < 2; ++rt) {                                              \
        bf16x4 hv_;                                                                                   \
        _Pragma("unroll") for (int r = 0; r < 4; ++r) {                                               \
          float pI = acc[rt][0][r], pF = acc[rt][1][r], pC = acc[rt][2][r], pO = acc[rt][3][r];       \
          float I_ = __builtin_amdgcn_rcpf(1.0f + __builtin_amdgcn_exp2f(pI * NL2E));                 \
          float F_ = __builtin_amdgcn_rcpf(1.0f + __builtin_amdgcn_exp2f(pF * NL2E));                 \
          float Ct_ = fmaf(-2.0f, __builtin_amdgcn_rcpf(1.0f + __builtin_amdgcn_exp2f(pC * T2L2E)), 1.0f); \
          float O_ = __builtin_amdgcn_rcpf(1.0f + __builtin_amdgcn_exp2f(pO * NL2E));                 \
          float Cn_ = fmaf(F_, Cst[rt][r], I_ * Ct_);                                                 \
          Cst[rt][r] = Cn_;                                                                           \
          float tC_ = fmaf(-2.0f, __builtin_amdgcn_rcpf(1.0f + __builtin_amdgcn_exp2f(Cn_ * T2L2E)), 1.0f); \
          float Hn_ = O_ * tC_;                                                                       \
          Ha[rt][r] = fmaf(pt_, Hn_, Ha[rt][r]);                                                      \
          hv_[r] = (bf16_t)Hn_;                                                                       \
        }                                                                                             \
        *(bf16x4*)(&Hs[WB][(rt * 16 + c0) * 256 + (((2 * w + (q >> 1)) ^ swz) << 4) + ((q & 1) * 8)]) = hv_; \
      }                                                                                               \
    }                                                                                                 \
    if (GAT) { G_DRAIN(); }                                                                           \
    if (LAST) {                                                                                       \
      G_SELF(soff_);                                                                                  \
      while (e < eTot) { G_ISSUE(soff_); G_DRAIN(); }                                                 \
      G_WRITE((((T) >> 2) + 1) & 1);                                                                  \
    }                                                                                                 \
    __syncthreads();                                                                                  \
  } while (0)

  GPER(0, 1, 0);
  GPER(1, 1, 0);
  GPER(2, 1, 0);
  GPER(3, 1, 1);
  GPER(4, 1, 0);
  GPER(5, 1, 0);
  GPER(6, 1, 0);
  GPER(7, 1, 1);
  GPER(8, 0, 0);
  GPER(9, 0, 0);
  GPER(10, 0, 0);
  GPER(11, 0, 0);
#undef GPER
#undef G_ISSUE
#undef G_DRAIN
#undef G_SELF
#undef G_WRITE

#pragma unroll
  for (int rt = 0; rt < 2; ++rt) {
    int row = n0 + rt * 16 + c0;
    *(floatx4*)(out + (size_t)row * 128 + w * 16 + q * 4) = Ha[rt];
  }
}

// ---------------- host ----------------
extern "C" void kernel_launch(void* const* d_in, const int* in_sizes, int n_in,
                              void* d_out, int out_size, void* d_ws, size_t ws_size,
                              hipStream_t stream) {
  const float* X = (const float*)d_in[0];
  const int* ei = (const int*)d_in[1];
  const float* ew = (const float*)d_in[2];
  const float* att = (const float*)d_in[3];
  const float* Wxi = (const float*)d_in[4];
  const float* bxi = (const float*)d_in[5];
  const float* Whi = (const float*)d_in[6];
  const float* bhi = (const float*)d_in[7];
  const float* Wxf = (const float*)d_in[8];
  const float* bxf = (const float*)d_in[9];
  const float* Whf = (const float*)d_in[10];
  const float* bhf = (const float*)d_in[11];
  const float* Wxc = (const float*)d_in[12];
  const float* bxc = (const float*)d_in[13];
  const float* Whc = (const float*)d_in[14];
  const float* bhc = (const float*)d_in[15];
  const float* Wxo = (const float*)d_in[16];
  const float* bxo = (const float*)d_in[17];
  const float* Who = (const float*)d_in[18];
  const float* bho = (const float*)d_in[19];
  float* out = (float*)d_out;

  const int N = in_sizes[0] / XROW;  // 40000
  const int E = in_sizes[2];         // 640000

  char* base = (char*)d_ws;
  size_t off = 0;
  auto carve = [&](size_t bytes) {
    char* r = base + off;
    off += (bytes + 255) & ~(size_t)255;
    return (void*)r;
  };
  float* deg = (float*)carve((size_t)N * 4);  // becomes dinv in-place
  int* counts = (int*)carve((size_t)N * 4);
  int* offs = (int*)carve((size_t)(N + 1) * 4);
  int* cursor = (int*)carve((size_t)(N + 1) * 4);
  int* csr_src = (int*)carve((size_t)E * 4);
  float* csr_nrm = (float*)carve((size_t)E * 4);
  bf16_t* WbT = (bf16_t*)carve((size_t)512 * 192 * 2);
  float* bcomb = (float*)carve(512 * 4);
  float* probs = (float*)carve(64);
  int* bsum = (int*)carve(64 * 4);
  bf16_t* Xb = (bf16_t*)carve((size_t)N * XROW * 2);
  // fallback-only buffer aliases Xb (fallback never uses Xb)
  bf16_t* Xagg = Xb;
  const bool use_bf16 = (off <= ws_size) && ((N & 31) == 0);

  k_init<<<(N + 255) / 256, 256, 0, stream>>>(deg, counts, N);
  k_accum<<<(E + 255) / 256, 256, 0, stream>>>(ei, ew, deg, counts, E);
  const int nb = (N + 1023) >> 10;
  if (nb <= 64) {
    k_scanA<<<nb, 256, 0, stream>>>(counts, deg, bsum, N);  // + dinv folded in
    k_scanC<<<nb, 256, 0, stream>>>(counts, bsum, offs, cursor, N, nb);
  } else {
    k_dinv<<<(N + 255) / 256, 256, 0, stream>>>(deg, N);
    k_scan<<<1, 1024, 0, stream>>>(counts, offs, cursor, N);
  }

  const int nbScatter = (E + 255) / 256;
  const int nbPrew = (512 * 192 + 512 + 1 + 255) / 256;
  if (use_bf16) {
    // fused: scatter | prew | xpose
    k_mid<<<nbScatter + nbPrew + N, 256, 0, stream>>>(
        ei, ew, deg, cursor, csr_src, csr_nrm, E,
        Wxi, Whi, Wxf, Whf, Wxc, Whc, Wxo, Who,
        bxi, bhi, bxf, bhf, bxc, bhc, bxo, bho, att, WbT, bcomb, probs,
        X, Xb, nbScatter, nbPrew);
    // fused gather + gate (replaces k_agg2 + k_gate_all)
    k_gate_fused<<<N / 32, 512, 0, stream>>>(Xb, csr_src, csr_nrm, offs, deg, WbT, bcomb, probs, out, N);
  } else {
    k_scatter<<<nbScatter, 256, 0, stream>>>(ei, ew, deg, cursor, csr_src, csr_nrm, E);
    k_prew<<<nbPrew, 256, 0, stream>>>(
        Wxi, Whi, Wxf, Whf, Wxc, Whc, Wxo, Who,
        bxi, bhi, bxf, bhf, bxc, bhc, bxo, bho, att, WbT, bcomb, probs);
    k_agg<<<N, 256, 0, stream>>>(X, csr_src, csr_nrm, offs, deg, Xagg, N);
    k_gate_all<<<N / 32, 512, 0, stream>>>(Xagg, WbT, bcomb, probs, out, N);
  }
}

// Round 6
// 598.369 us; speedup vs baseline: 1.8311x; 1.8311x over previous
//
#include <hip/hip_runtime.h>

typedef __bf16 bf16_t;
typedef bf16_t bf16x4 __attribute__((ext_vector_type(4)));
typedef bf16_t bf16x8 __attribute__((ext_vector_type(8)));
typedef float floatx4 __attribute__((ext_vector_type(4)));

#define F_INq 64
#define F_OUTq 128
#define PERIODSq 12
#define XROW (F_INq * PERIODSq) /* 768 */

// ---------------- degree / CSR build ----------------
// fallback-path init (main path uses one hipMemsetAsync over deg+counts)
__global__ __launch_bounds__(256) void k_init(float* deg, int* counts, int N) {
  int i = blockIdx.x * 256 + threadIdx.x;
  if (i < N) { deg[i] = 1.0f; counts[i] = 0; }  // self-loop weight 1
}

__global__ __launch_bounds__(256) void k_accum(const int* __restrict__ ei, const float* __restrict__ ew,
                                               float* deg, int* counts, int E) {
  int e = blockIdx.x * 256 + threadIdx.x;
  if (e < E) {
    int c = ei[E + e];  // target
    atomicAdd(&deg[c], ew[e]);
    atomicAdd(&counts[c], 1);
  }
}

// fallback-path dinv (main path folds dinv into k_scanA)
__global__ __launch_bounds__(256) void k_dinv(float* deg, int N) {
  int i = blockIdx.x * 256 + threadIdx.x;
  if (i < N) { float d = deg[i]; deg[i] = d > 0.0f ? rsqrtf(d) : 0.0f; }
}

// ---------------- multi-block scan ----------------
// A: per-1024-chunk sums + dinv. Main path: deg was memset to 0, accum added edge
// weights; self-loop weight 1 folded analytically -> dinv = rsqrt(deg + 1) (always > 0).
__global__ __launch_bounds__(256) void k_scanA(const int* __restrict__ counts, float* __restrict__ deg,
                                               int* __restrict__ bsum, int N) {
  __shared__ int ws[4];
  int b = blockIdx.x, t = threadIdx.x;
  int base = b * 1024 + t * 4;
  int s = 0;
  if (base + 3 < N) {
    int4 c = *(const int4*)(counts + base);
    s = c.x + c.y + c.z + c.w;
  } else {
    for (int k = 0; k < 4; ++k) if (base + k < N) s += counts[base + k];
  }
#pragma unroll
  for (int k = 0; k < 4; ++k) {
    int idx = base + k;
    if (idx < N) { deg[idx] = rsqrtf(deg[idx] + 1.0f); }
  }
  for (int off = 1; off < 64; off <<= 1) s += __shfl_xor(s, off);
  int lane = t & 63, w = t >> 6;
  if (lane == 0) ws[w] = s;
  __syncthreads();
  if (t == 0) bsum[b] = ws[0] + ws[1] + ws[2] + ws[3];
}

// C: per-chunk local scan + base (block base recomputed redundantly from bsum; nb<=64)
__global__ __launch_bounds__(256) void k_scanC(const int* __restrict__ counts, const int* __restrict__ bsum,
                                               int* __restrict__ offs, int* __restrict__ cursor, int N, int nb) {
  __shared__ int ws[4];
  int b = blockIdx.x, t = threadIdx.x;
  int base = b * 1024 + t * 4;
  int c0_ = 0, c1_ = 0, c2_ = 0, c3_ = 0;
  if (base + 3 < N) {
    int4 c = *(const int4*)(counts + base);
    c0_ = c.x; c1_ = c.y; c2_ = c.z; c3_ = c.w;
  } else {
    if (base < N) c0_ = counts[base];
    if (base + 1 < N) c1_ = counts[base + 1];
    if (base + 2 < N) c2_ = counts[base + 2];
    if (base + 3 < N) c3_ = counts[base + 3];
  }
  int tot = c0_ + c1_ + c2_ + c3_;
  int lane = t & 63, w = t >> 6;
  int inc = tot;
  for (int off = 1; off < 64; off <<= 1) {
    int u = __shfl_up(inc, off);
    if (lane >= off) inc += u;
  }
  if (lane == 63) ws[w] = inc;
  __syncthreads();
  int wb = 0;  // exclusive prefix of block sums (uniform scalar loop, nb<=64, L2-hot)
  for (int i = 0; i < b; ++i) wb += bsum[i];
  for (int i = 0; i < w; ++i) wb += ws[i];
  int e = wb + inc - tot;
  if (base < N)     { offs[base] = e;                 cursor[base] = e; }
  if (base + 1 < N) { int o = e + c0_;                offs[base + 1] = o; cursor[base + 1] = o; }
  if (base + 2 < N) { int o = e + c0_ + c1_;          offs[base + 2] = o; cursor[base + 2] = o; }
  if (base + 3 < N) { int o = e + c0_ + c1_ + c2_;    offs[base + 3] = o; cursor[base + 3] = o; }
  if (b == nb - 1 && t == 0) {
    int tt2 = 0;
    for (int i = 0; i < nb - 1; ++i) tt2 += bsum[i];
    offs[N] = tt2 + ws[0] + ws[1] + ws[2] + ws[3];
  }
}

// fallback single-block scan (only if nb > 64; N=40000 -> never)
__global__ __launch_bounds__(1024) void k_scan(const int* __restrict__ counts, int* __restrict__ offs,
                                               int* __restrict__ cursor, int N) {
  __shared__ int sd[1024];
  int t = threadIdx.x;
  int CH = (N + 1023) >> 10;
  int base = t * CH;
  int sum = 0;
  for (int i = 0; i < CH; ++i) { int idx = base + i; if (idx < N) sum += counts[idx]; }
  sd[t] = sum;
  __syncthreads();
  for (int off = 1; off < 1024; off <<= 1) {
    int v = (t >= off) ? sd[t - off] : 0;
    __syncthreads();
    sd[t] += v;
    __syncthreads();
  }
  int run = sd[t] - sum;  // exclusive prefix
  for (int i = 0; i < CH; ++i) {
    int idx = base + i;
    if (idx < N) { offs[idx] = run; cursor[idx] = run; run += counts[idx]; }
  }
  if (t == 1023) offs[N] = sd[1023];
}

// standalone fallbacks (used only on the fp32 fallback path)
__global__ __launch_bounds__(256) void k_scatter(const int* __restrict__ ei, const float* __restrict__ ew,
                                                 const float* __restrict__ dinv, int* cursor,
                                                 int* __restrict__ csr_src, float* __restrict__ csr_nrm, int E) {
  int e = blockIdx.x * 256 + threadIdx.x;
  if (e < E) {
    int r = ei[e], c = ei[E + e];
    int p = atomicAdd(&cursor[c], 1);
    csr_src[p] = r;
    csr_nrm[p] = dinv[r] * ew[e] * dinv[c];
  }
}

__global__ __launch_bounds__(256) void k_prew(
    const float* __restrict__ Wxi, const float* __restrict__ Whi,
    const float* __restrict__ Wxf, const float* __restrict__ Whf,
    const float* __restrict__ Wxc, const float* __restrict__ Whc,
    const float* __restrict__ Wxo, const float* __restrict__ Who,
    const float* __restrict__ bxi, const float* __restrict__ bhi,
    const float* __restrict__ bxf, const float* __restrict__ bhf,
    const float* __restrict__ bxc, const float* __restrict__ bhc,
    const float* __restrict__ bxo, const float* __restrict__ bho,
    const float* __restrict__ att,
    bf16_t* __restrict__ WbT, float* __restrict__ bcomb, float* __restrict__ probs) {
  const int WT = 512 * 192;
  int gid = blockIdx.x * 256 + threadIdx.x;
  if (gid < WT) {
    int col = gid / 192, k = gid % 192;
    int g = col >> 7, j = col & 127;
    const float* Wx = g == 0 ? Wxi : g == 1 ? Wxf : g == 2 ? Wxc : Wxo;
    const float* Wh = g == 0 ? Whi : g == 1 ? Whf : g == 2 ? Whc : Who;
    float s;
    if (k < 64) {
      s = 0.0f;
      for (int kk = 0; kk < 128; ++kk) s += Wx[k * 128 + kk] * Wh[kk * 128 + j];
    } else {
      s = Wh[(k + 64) * 128 + j];
    }
    WbT[(size_t)col * 192 + k] = (bf16_t)s;
  } else if (gid < WT + 512) {
    int cc = gid - WT;
    int g = cc >> 7, j = cc & 127;
    const float* bx = g == 0 ? bxi : g == 1 ? bxf : g == 2 ? bxc : bxo;
    const float* bh = g == 0 ? bhi : g == 1 ? bhf : g == 2 ? bhc : bho;
    const float* Wh = g == 0 ? Whi : g == 1 ? Whf : g == 2 ? Whc : Who;
    float s = bh[j];
    for (int kk = 0; kk < 128; ++kk) s += bx[kk] * Wh[kk * 128 + j];
    bcomb[cc] = s;
  } else if (gid == WT + 512) {
    float m = att[0];
    for (int i = 1; i < PERIODSq; ++i) m = fmaxf(m, att[i]);
    float e[PERIODSq], s = 0.0f;
    for (int i = 0; i < PERIODSq; ++i) { e[i] = __expf(att[i] - m); s += e[i]; }
    for (int i = 0; i < PERIODSq; ++i) probs[i] = e[i] / s;
  }
}

// ---------------- fused mid-pipeline: scatter | prew | xpose in ONE dispatch ----------------
__global__ __launch_bounds__(256) void k_mid(
    const int* __restrict__ ei, const float* __restrict__ ew, const float* __restrict__ dinv,
    int* cursor, int* __restrict__ csr_src, float* __restrict__ csr_nrm, int E,
    const float* __restrict__ Wxi, const float* __restrict__ Whi,
    const float* __restrict__ Wxf, const float* __restrict__ Whf,
    const float* __restrict__ Wxc, const float* __restrict__ Whc,
    const float* __restrict__ Wxo, const float* __restrict__ Who,
    const float* __restrict__ bxi, const float* __restrict__ bhi,
    const float* __restrict__ bxf, const float* __restrict__ bhf,
    const float* __restrict__ bxc, const float* __restrict__ bhc,
    const float* __restrict__ bxo, const float* __restrict__ bho,
    const float* __restrict__ att,
    bf16_t* __restrict__ WbT, float* __restrict__ bcomb, float* __restrict__ probs,
    const float* __restrict__ X, bf16_t* __restrict__ Xb,
    int nbScatter, int nbPrew) {
  __shared__ float lds[XROW];
  const int b = blockIdx.x, tid = threadIdx.x;
  if (b < nbScatter) {
    int e = b * 256 + tid;
    if (e < E) {
      int r = ei[e], c = ei[E + e];
      int p = atomicAdd(&cursor[c], 1);
      csr_src[p] = r;
      csr_nrm[p] = dinv[r] * ew[e] * dinv[c];
    }
    return;
  }
  if (b < nbScatter + nbPrew) {
    const int WT = 512 * 192;
    int gid = (b - nbScatter) * 256 + tid;
    if (gid < WT) {
      int col = gid / 192, k = gid % 192;
      int g = col >> 7, j = col & 127;
      const float* Wx = g == 0 ? Wxi : g == 1 ? Wxf : g == 2 ? Wxc : Wxo;
      const float* Wh = g == 0 ? Whi : g == 1 ? Whf : g == 2 ? Whc : Who;
      float s;
      if (k < 64) {
        s = 0.0f;
        for (int kk = 0; kk < 128; ++kk) s += Wx[k * 128 + kk] * Wh[kk * 128 + j];
      } else {
        s = Wh[(k + 64) * 128 + j];
      }
      WbT[(size_t)col * 192 + k] = (bf16_t)s;
    } else if (gid < WT + 512) {
      int cc = gid - WT;
      int g = cc >> 7, j = cc & 127;
      const float* bx = g == 0 ? bxi : g == 1 ? bxf : g == 2 ? bxc : bxo;
      const float* bh = g == 0 ? bhi : g == 1 ? bhf : g == 2 ? bhc : bho;
      const float* Wh = g == 0 ? Whi : g == 1 ? Whf : g == 2 ? Whc : Who;
      float s = bh[j];
      for (int kk = 0; kk < 128; ++kk) s += bx[kk] * Wh[kk * 128 + j];
      bcomb[cc] = s;
    } else if (gid == WT + 512) {
      float m = att[0];
      for (int i = 1; i < PERIODSq; ++i) m = fmaxf(m, att[i]);
      float e[PERIODSq], s = 0.0f;
      for (int i = 0; i < PERIODSq; ++i) { e[i] = __expf(att[i] - m); s += e[i]; }
      for (int i = 0; i < PERIODSq; ++i) probs[i] = e[i] / s;
    }
    return;
  }
  // xpose: X[n][f][t] fp32 -> Xb[n][t*64+f] bf16 (threads 0..191 active, barrier uniform)
  const int n = b - nbScatter - nbPrew;
  if (tid < 192) {
    const float4* Xr = (const float4*)(X + (size_t)n * XROW);
    float4 v = Xr[tid];
    lds[tid * 4 + 0] = v.x;
    lds[tid * 4 + 1] = v.y;
    lds[tid * 4 + 2] = v.z;
    lds[tid * 4 + 3] = v.w;
  }
  __syncthreads();
  if (tid < 192) {
    const int o = tid * 4;
    bf16x4 r;
#pragma unroll
    for (int k = 0; k < 4; ++k) {
      int oo = o + k;
      int tt = oo >> 6, f = oo & 63;
      r[k] = (bf16_t)lds[f * PERIODSq + tt];
    }
    *(bf16x4*)(Xb + (size_t)n * XROW + o) = r;
  }
}

// ---------------- aggregation (bf16 gather): Xagg[t][n][64] = A_norm @ X ----------------
// one wave per node; 8-edge batches, 512B/request. Round-5 post-mortem: bandwidth-delay
// analysis says this is L2-miss-path BW-bound (3.35 TB/s fetch), not latency-bound ->
// left untouched (round-3 t-split and round-5 fusion both regressed it).
__global__ __launch_bounds__(256) void k_agg2(const bf16_t* __restrict__ Xb, const int* __restrict__ csr_src,
                                              const float* __restrict__ csr_nrm, const int* __restrict__ offs,
                                              const float* __restrict__ dinv, bf16_t* __restrict__ Xagg, int N) {
  const int node = blockIdx.x * 4 + (threadIdx.x >> 6);
  const int lane = threadIdx.x & 63;
  const int s0 = offs[node], s1 = offs[node + 1];
  floatx4 a0 = {0.f, 0.f, 0.f, 0.f}, a1 = a0, a2 = a0;
  int e = s0;
  for (; e + 8 <= s1; e += 8) {
    bf16x4 v[8][3];
    float nn[8];
#pragma unroll
    for (int u = 0; u < 8; ++u) {
      int s = csr_src[e + u];
      nn[u] = csr_nrm[e + u];
      const bf16x4* xp = (const bf16x4*)(Xb + (size_t)s * XROW) + lane;
      v[u][0] = xp[0]; v[u][1] = xp[64]; v[u][2] = xp[128];
    }
#pragma unroll
    for (int u = 0; u < 8; ++u) {
#pragma unroll
      for (int k = 0; k < 4; ++k) {
        a0[k] += nn[u] * (float)v[u][0][k];
        a1[k] += nn[u] * (float)v[u][1][k];
        a2[k] += nn[u] * (float)v[u][2][k];
      }
    }
  }
  for (; e < s1; ++e) {
    int s = csr_src[e];
    float nr = csr_nrm[e];
    const bf16x4* xp = (const bf16x4*)(Xb + (size_t)s * XROW) + lane;
    bf16x4 v0 = xp[0], v1 = xp[64], v2 = xp[128];
#pragma unroll
    for (int k = 0; k < 4; ++k) {
      a0[k] += nr * (float)v0[k];
      a1[k] += nr * (float)v1[k];
      a2[k] += nr * (float)v2[k];
    }
  }
  float dc = dinv[node];
  float self = dc * dc;
  const bf16x4* xc = (const bf16x4*)(Xb + (size_t)node * XROW) + lane;
  {
    bf16x4 v0 = xc[0], v1 = xc[64], v2 = xc[128];
#pragma unroll
    for (int k = 0; k < 4; ++k) {
      a0[k] += self * (float)v0[k];
      a1[k] += self * (float)v1[k];
      a2[k] += self * (float)v2[k];
    }
  }
  const int f4 = lane & 15, tq = lane >> 4;
  floatx4 accs[3] = {a0, a1, a2};
#pragma unroll
  for (int j = 0; j < 3; ++j) {
    int tt = tq + 4 * j;
    bf16x4 r;
#pragma unroll
    for (int k = 0; k < 4; ++k) r[k] = (bf16_t)accs[j][k];
    *(bf16x4*)(Xagg + ((size_t)tt * N + node) * 64 + f4 * 4) = r;
  }
}

// ---------------- fallback aggregation (fp32 gather, used only if ws too small) ----------------
__global__ __launch_bounds__(256) void k_agg(const float* __restrict__ X, const int* __restrict__ csr_src,
                                             const float* __restrict__ csr_nrm, const int* __restrict__ offs,
                                             const float* __restrict__ dinv, bf16_t* __restrict__ Xagg, int N) {
  int c = blockIdx.x;
  int tid = threadIdx.x;
  int s0 = offs[c], s1 = offs[c + 1];
  const int i0 = tid, i1 = tid + 256, i2 = tid + 512;
  float a0 = 0.f, a1 = 0.f, a2 = 0.f;
  for (int e = s0; e < s1; ++e) {
    int s = csr_src[e];
    float nr = csr_nrm[e];
    const float* xp = X + (size_t)s * XROW;
    a0 += nr * xp[i0]; a1 += nr * xp[i1]; a2 += nr * xp[i2];
  }
  float dc = dinv[c];
  float self = dc * dc;
  const float* xc = X + (size_t)c * XROW;
  a0 += self * xc[i0]; a1 += self * xc[i1]; a2 += self * xc[i2];
  __shared__ float lds[XROW];
  lds[i0] = a0; lds[i1] = a1; lds[i2] = a2;
  __syncthreads();
  for (int o = tid; o < XROW; o += 256) {
    int tt = o >> 6, f = o & 63;
    Xagg[(size_t)tt * N * 64 + (size_t)c * 64 + f] = (bf16_t)lds[f * PERIODSq + tt];
  }
}

// ---------------- persistent fused LSTM, W-stationary ----------------
// Round-6 change: break the MFMA<->VALU phase alternation inside each period.
// (Occupancy is structurally capped at 1 block/CU: Wf 96 + acc regs ~180 total incl.
// accumulators -> 2 waves/SIMD; VGPR_Count in rocprof excludes MFMA acc regs.)
// New per-period order: H-MFMA(rt0) | H-MFMA(rt1) | epilogue(rt0) [overlaps rt1 MFMAs]
// | next-period X-part MFMAs [independent, feeds matrix pipe during epilogues]
// | epilogue(rt1) | barrier. Everything else as verified in rounds 2-4.
__global__ __launch_bounds__(512, 2) void k_gate_all(const bf16_t* __restrict__ Xagg,
                                                     const bf16_t* __restrict__ WbT,
                                                     const float* __restrict__ bcomb,
                                                     const float* __restrict__ probs,
                                                     float* __restrict__ out, int N) {
  __shared__ __align__(16) char Hs[2][32 * 256];
  const int tid = threadIdx.x;
  const int lane = tid & 63, w = tid >> 6;
  const int q = lane >> 4, c0 = lane & 15;
  const int n0 = blockIdx.x * 32;
  const int swz = c0 & 7;

  bf16x8 Wf[4][6];
#pragma unroll
  for (int g = 0; g < 4; ++g) {
    const bf16_t* wp = WbT + (size_t)((g * 8 + w) * 16 + c0) * 192;
#pragma unroll
    for (int ks = 0; ks < 6; ++ks) Wf[g][ks] = *(const bf16x8*)(wp + ks * 32 + q * 8);
  }
  floatx4 bv[4];
#pragma unroll
  for (int g = 0; g < 4; ++g) bv[g] = *(const floatx4*)(bcomb + g * 128 + w * 16 + q * 4);
  float pr[PERIODSq];
#pragma unroll
  for (int i = 0; i < PERIODSq; ++i) pr[i] = probs[i];

  floatx4 Cst[2], Ha[2];
#pragma unroll
  for (int rt = 0; rt < 2; ++rt) {
    Cst[rt] = (floatx4){0.f, 0.f, 0.f, 0.f};
    Ha[rt] = (floatx4){0.f, 0.f, 0.f, 0.f};
  }

  const bf16_t* Xrow0 = Xagg + (size_t)(n0 + c0) * 64 + q * 8;
  const bf16_t* Xrow1 = Xagg + (size_t)(n0 + 16 + c0) * 64 + q * 8;

  bf16x8 Xf0 = *(const bf16x8*)(Xrow0);
  bf16x8 Xf1 = *(const bf16x8*)(Xrow0 + 32);
  bf16x8 Xf2 = *(const bf16x8*)(Xrow1);
  bf16x8 Xf3 = *(const bf16x8*)(Xrow1 + 32);

  floatx4 accA[2][4], accB[2][4];
#pragma unroll
  for (int g = 0; g < 4; ++g) {
    accA[0][g] = __builtin_amdgcn_mfma_f32_16x16x32_bf16(Wf[g][0], Xf0, bv[g], 0, 0, 0);
    accA[0][g] = __builtin_amdgcn_mfma_f32_16x16x32_bf16(Wf[g][1], Xf1, accA[0][g], 0, 0, 0);
    accA[1][g] = __builtin_amdgcn_mfma_f32_16x16x32_bf16(Wf[g][0], Xf2, bv[g], 0, 0, 0);
    accA[1][g] = __builtin_amdgcn_mfma_f32_16x16x32_bf16(Wf[g][1], Xf3, accA[1][g], 0, 0, 0);
  }

  const float NL2E = -1.44269504f;  // -log2(e)
  const float T2L2E = 2.88539008f;  // 2*log2(e)

  // per-rt epilogue: gate math + LDS H-write (depends only on AC[RT])
#define EPI(AC, RT, WB, PT)                                                                           \
  {                                                                                                   \
    bf16x4 hv_;                                                                                       \
    _Pragma("unroll") for (int r = 0; r < 4; ++r) {                                                   \
      float pI = AC[RT][0][r], pF = AC[RT][1][r], pC = AC[RT][2][r], pO = AC[RT][3][r];               \
      float I_ = __builtin_amdgcn_rcpf(1.0f + __builtin_amdgcn_exp2f(pI * NL2E));                     \
      float F_ = __builtin_amdgcn_rcpf(1.0f + __builtin_amdgcn_exp2f(pF * NL2E));                     \
      float Ct_ = fmaf(-2.0f, __builtin_amdgcn_rcpf(1.0f + __builtin_amdgcn_exp2f(pC * T2L2E)), 1.0f); \
      float O_ = __builtin_amdgcn_rcpf(1.0f + __builtin_amdgcn_exp2f(pO * NL2E));                     \
      float Cn_ = fmaf(F_, Cst[RT][r], I_ * Ct_);                                                     \
      Cst[RT][r] = Cn_;                                                                               \
      float tC_ = fmaf(-2.0f, __builtin_amdgcn_rcpf(1.0f + __builtin_amdgcn_exp2f(Cn_ * T2L2E)), 1.0f); \
      float Hn_ = O_ * tC_;                                                                           \
      Ha[RT][r] = fmaf(PT, Hn_, Ha[RT][r]);                                                           \
      hv_[r] = (bf16_t)Hn_;                                                                           \
    }                                                                                                 \
    *(bf16x4*)(&Hs[WB][((RT) * 16 + c0) * 256 + (((2 * w + (q >> 1)) ^ swz) << 4) + ((q & 1) * 8)]) = hv_; \
  }

#define PERIOD(T, AC, AN, RB, WB, DO_H, DO_NEXT)                                                      \
  do {                                                                                                \
    if (DO_NEXT) {                                                                                    \
      const size_t toff_ = (size_t)((T) + 1) * N * 64;                                                \
      Xf0 = *(const bf16x8*)(Xrow0 + toff_);                                                          \
      Xf1 = *(const bf16x8*)(Xrow0 + toff_ + 32);                                                     \
      Xf2 = *(const bf16x8*)(Xrow1 + toff_);                                                          \
      Xf3 = *(const bf16x8*)(Xrow1 + toff_ + 32);                                                     \
    }                                                                                                 \
    if (DO_H) {                                                                                       \
      _Pragma("unroll") for (int ks = 0; ks < 4; ++ks) {                                              \
        bf16x8 B0 = *(const bf16x8*)(&Hs[RB][(c0) * 256 + (((4 * ks + q) ^ swz) << 4)]);              \
        _Pragma("unroll") for (int g = 0; g < 4; ++g)                                                 \
          AC[0][g] = __builtin_amdgcn_mfma_f32_16x16x32_bf16(Wf[g][ks + 2], B0, AC[0][g], 0, 0, 0);   \
      }                                                                                               \
      _Pragma("unroll") for (int ks = 0; ks < 4; ++ks) {                                              \
        bf16x8 B1 = *(const bf16x8*)(&Hs[RB][(16 + c0) * 256 + (((4 * ks + q) ^ swz) << 4)]);         \
        _Pragma("unroll") for (int g = 0; g < 4; ++g)                                                 \
          AC[1][g] = __builtin_amdgcn_mfma_f32_16x16x32_bf16(Wf[g][ks + 2], B1, AC[1][g], 0, 0, 0);   \
      }                                                                                               \
    }                                                                                                 \
    const float pt_ = pr[T];                                                                          \
    EPI(AC, 0, WB, pt_)              /* rt0 epilogue: overlaps rt1 H-MFMAs above */                   \
    if (DO_NEXT) {                   /* next-period X-part: feeds matrix pipe during epilogues */     \
      _Pragma("unroll") for (int g = 0; g < 4; ++g) {                                                 \
        AN[0][g] = __builtin_amdgcn_mfma_f32_16x16x32_bf16(Wf[g][0], Xf0, bv[g], 0, 0, 0);            \
        AN[0][g] = __builtin_amdgcn_mfma_f32_16x16x32_bf16(Wf[g][1], Xf1, AN[0][g], 0, 0, 0);         \
        AN[1][g] = __builtin_amdgcn_mfma_f32_16x16x32_bf16(Wf[g][0], Xf2, bv[g], 0, 0, 0);            \
        AN[1][g] = __builtin_amdgcn_mfma_f32_16x16x32_bf16(Wf[g][1], Xf3, AN[1][g], 0, 0, 0);         \
      }                                                                                               \
    }                                                                                                 \
    EPI(AC, 1, WB, pt_)                                                                               \
    __syncthreads();                                                                                  \
  } while (0)

  PERIOD(0, accA, accB, 1, 0, 0, 1);
  for (int tt = 1; tt <= 9; tt += 2) {
    PERIOD(tt, accB, accA, 0, 1, 1, 1);
    PERIOD(tt + 1, accA, accB, 1, 0, 1, 1);
  }
  PERIOD(11, accB, accA, 0, 1, 1, 0);
#undef PERIOD
#undef EPI

#pragma unroll
  for (int rt = 0; rt < 2; ++rt) {
    int row = n0 + rt * 16 + c0;
    *(floatx4*)(out + (size_t)row * 128 + w * 16 + q * 4) = Ha[rt];
  }
}

// ---------------- host ----------------
extern "C" void kernel_launch(void* const* d_in, const int* in_sizes, int n_in,
                              void* d_out, int out_size, void* d_ws, size_t ws_size,
                              hipStream_t stream) {
  const float* X = (const float*)d_in[0];
  const int* ei = (const int*)d_in[1];
  const float* ew = (const float*)d_in[2];
  const float* att = (const float*)d_in[3];
  const float* Wxi = (const float*)d_in[4];
  const float* bxi = (const float*)d_in[5];
  const float* Whi = (const float*)d_in[6];
  const float* bhi = (const float*)d_in[7];
  const float* Wxf = (const float*)d_in[8];
  const float* bxf = (const float*)d_in[9];
  const float* Whf = (const float*)d_in[10];
  const float* bhf = (const float*)d_in[11];
  const float* Wxc = (const float*)d_in[12];
  const float* bxc = (const float*)d_in[13];
  const float* Whc = (const float*)d_in[14];
  const float* bhc = (const float*)d_in[15];
  const float* Wxo = (const float*)d_in[16];
  const float* bxo = (const float*)d_in[17];
  const float* Who = (const float*)d_in[18];
  const float* bho = (const float*)d_in[19];
  float* out = (float*)d_out;

  const int N = in_sizes[0] / XROW;  // 40000
  const int E = in_sizes[2];         // 640000

  char* base = (char*)d_ws;
  size_t off = 0;
  auto carve = [&](size_t bytes) {
    char* r = base + off;
    off += (bytes + 255) & ~(size_t)255;
    return (void*)r;
  };
  float* deg = (float*)carve((size_t)N * 4);  // becomes dinv in-place
  int* counts = (int*)carve((size_t)N * 4);
  int* offs = (int*)carve((size_t)(N + 1) * 4);
  int* cursor = (int*)carve((size_t)(N + 1) * 4);
  int* csr_src = (int*)carve((size_t)E * 4);
  float* csr_nrm = (float*)carve((size_t)E * 4);
  bf16_t* WbT = (bf16_t*)carve((size_t)512 * 192 * 2);
  float* bcomb = (float*)carve(512 * 4);
  float* probs = (float*)carve(64);
  int* bsum = (int*)carve(64 * 4);
  bf16_t* Xagg = (bf16_t*)carve((size_t)PERIODSq * N * 64 * 2);
  bf16_t* Xb = (bf16_t*)carve((size_t)N * XROW * 2);
  const bool use_bf16 = (off <= ws_size) && ((N & 31) == 0);

  const int nb = (N + 1023) >> 10;
  if (nb <= 64) {
    // deg and counts are contiguous carves (both zero-init): one memset replaces k_init;
    // self-loop folded into scanA's rsqrt(deg+1)
    size_t degspan = ((size_t)N * 4 + 255) & ~(size_t)255;
    hipMemsetAsync(deg, 0, degspan + (size_t)N * 4, stream);
    k_accum<<<(E + 255) / 256, 256, 0, stream>>>(ei, ew, deg, counts, E);
    k_scanA<<<nb, 256, 0, stream>>>(counts, deg, bsum, N);  // + dinv folded in
    k_scanC<<<nb, 256, 0, stream>>>(counts, bsum, offs, cursor, N, nb);
  } else {
    k_init<<<(N + 255) / 256, 256, 0, stream>>>(deg, counts, N);
    k_accum<<<(E + 255) / 256, 256, 0, stream>>>(ei, ew, deg, counts, E);
    k_dinv<<<(N + 255) / 256, 256, 0, stream>>>(deg, N);
    k_scan<<<1, 1024, 0, stream>>>(counts, offs, cursor, N);
  }

  const int nbScatter = (E + 255) / 256;
  const int nbPrew = (512 * 192 + 512 + 1 + 255) / 256;
  if (use_bf16) {
    // fused: scatter | prew | xpose
    k_mid<<<nbScatter + nbPrew + N, 256, 0, stream>>>(
        ei, ew, deg, cursor, csr_src, csr_nrm, E,
        Wxi, Whi, Wxf, Whf, Wxc, Whc, Wxo, Who,
        bxi, bhi, bxf, bhf, bxc, bhc, bxo, bho, att, WbT, bcomb, probs,
        X, Xb, nbScatter, nbPrew);
    k_agg2<<<N / 4, 256, 0, stream>>>(Xb, csr_src, csr_nrm, offs, deg, Xagg, N);
    k_gate_all<<<N / 32, 512, 0, stream>>>(Xagg, WbT, bcomb, probs, out, N);
  } else {
    k_scatter<<<nbScatter, 256, 0, stream>>>(ei, ew, deg, cursor, csr_src, csr_nrm, E);
    k_prew<<<nbPrew, 256, 0, stream>>>(
        Wxi, Whi, Wxf, Whf, Wxc, Whc, Wxo, Who,
        bxi, bhi, bxf, bhf, bxc, bhc, bxo, bho, att, WbT, bcomb, probs);
    k_agg<<<N, 256, 0, stream>>>(X, csr_src, csr_nrm, offs, deg, Xagg, N);
    k_gate_all<<<N / 32, 512, 0, stream>>>(Xagg, WbT, bcomb, probs, out, N);
  }
}